// Round 4
// baseline (666.885 us; speedup 1.0000x reference)
//
#include <hip/hip_runtime.h>
#include <hip/hip_bf16.h>
#include <math.h>

#define Bn 8
#define Nn 8192
#define KIN 1024
#define DOUT 512
#define NC 64
#define LN_EPS 1e-5f

typedef short bf16x8 __attribute__((ext_vector_type(8)));
typedef short s8v __attribute__((ext_vector_type(8)));
typedef short s4v __attribute__((ext_vector_type(4)));
typedef float f32x4 __attribute__((ext_vector_type(4)));

__device__ __forceinline__ short f2bf(float f) {
    __hip_bfloat16 h = __float2bfloat16(f);
    return __builtin_bit_cast(short, h);
}

__device__ __forceinline__ bf16x8 cvt8(float4 u, float4 v) {
    bf16x8 r;
    r[0] = f2bf(u.x); r[1] = f2bf(u.y); r[2] = f2bf(u.z); r[3] = f2bf(u.w);
    r[4] = f2bf(v.x); r[5] = f2bf(v.y); r[6] = f2bf(v.z); r[7] = f2bf(v.w);
    return r;
}

// ---------------- prep: W_node^T -> bf16 [512][1024], LDS transpose ----------------
__global__ __launch_bounds__(256) void k_prep_w(const float* __restrict__ W,
                                                short* __restrict__ Wt) {
    __shared__ short L[64 * 72];
    const int tid = threadIdx.x;
    const int kt = blockIdx.x >> 3, nt = blockIdx.x & 7;   // 16 x 8 tiles of 64x64
    const int k0 = kt * 64, n0 = nt * 64;
    {
        int r = tid >> 2, c0 = (tid & 3) * 16;
        const float* g = W + (size_t)(k0 + r) * DOUT + n0 + c0;
        float4 a0 = *reinterpret_cast<const float4*>(g);
        float4 a1 = *reinterpret_cast<const float4*>(g + 4);
        float4 a2 = *reinterpret_cast<const float4*>(g + 8);
        float4 a3 = *reinterpret_cast<const float4*>(g + 12);
        *reinterpret_cast<s8v*>(&L[r * 72 + c0]) = cvt8(a0, a1);
        *reinterpret_cast<s8v*>(&L[r * 72 + c0 + 8]) = cvt8(a2, a3);
    }
    __syncthreads();
    {
        int n = tid >> 2, kc = (tid & 3) * 16;
        s8v y0, y1;
#pragma unroll
        for (int j = 0; j < 8; ++j) y0[j] = L[(kc + j) * 72 + n];
#pragma unroll
        for (int j = 0; j < 8; ++j) y1[j] = L[(kc + 8 + j) * 72 + n];
        short* o = Wt + (size_t)(n0 + n) * KIN + k0 + kc;
        *reinterpret_cast<s8v*>(o) = y0;
        *reinterpret_cast<s8v*>(o + 8) = y1;
    }
}

// ---------------- prep: ccp = cc @ Wc + bc (fp32 + bf16), ILP unroll ----------------
// grid 128 = (c, d-half of 256); 8-way k-unroll, 4 accumulators for ILP.
__global__ __launch_bounds__(256) void k_prep_c(
    const float* __restrict__ cc, const float* __restrict__ Wc,
    const float* __restrict__ bc, float* __restrict__ ccp_f,
    short* __restrict__ ccp_bf) {
    __shared__ float ccs[512];
    const int tid = threadIdx.x;
    const int c = blockIdx.x >> 1, d = (blockIdx.x & 1) * 256 + tid;
    ccs[tid] = cc[c * DOUT + tid];
    ccs[tid + 256] = cc[c * DOUT + tid + 256];
    __syncthreads();
    float a0 = bc[d], a1 = 0.f, a2 = 0.f, a3 = 0.f;
    for (int k = 0; k < DOUT; k += 8) {
        a0 += ccs[k + 0] * Wc[(size_t)(k + 0) * DOUT + d];
        a1 += ccs[k + 1] * Wc[(size_t)(k + 1) * DOUT + d];
        a2 += ccs[k + 2] * Wc[(size_t)(k + 2) * DOUT + d];
        a3 += ccs[k + 3] * Wc[(size_t)(k + 3) * DOUT + d];
        a0 += ccs[k + 4] * Wc[(size_t)(k + 4) * DOUT + d];
        a1 += ccs[k + 5] * Wc[(size_t)(k + 5) * DOUT + d];
        a2 += ccs[k + 6] * Wc[(size_t)(k + 6) * DOUT + d];
        a3 += ccs[k + 7] * Wc[(size_t)(k + 7) * DOUT + d];
    }
    float a = (a0 + a1) + (a2 + a3);
    ccp_f[c * DOUT + d] = a;
    ccp_bf[c * DOUT + d] = f2bf(a);
}

// ---------------- GEMM1: proj & projT = A(fp32) @ W + b ----------------
// Barrier-free direct-fragment GEMM: no LDS. Both operands are k-contiguous;
// each lane loads its MFMA fragment straight from global (A: HBM stream, read
// once since BN=512 full width; Wt: 1 MB, L2-resident). 256 thr / 4 waves,
// wave tile 64m x 128n, BK=32, 32 iters. Fully-used 64B lines per wave load.
__global__ __launch_bounds__(256, 2) void k_gemm1(
    const float* __restrict__ A, const short* __restrict__ Wt,
    const float* __restrict__ bias, short* __restrict__ proj,
    short* __restrict__ projT) {
    const int tid = threadIdx.x, lane = tid & 63, wv = tid >> 6;
    const int quad = lane >> 4, l15 = lane & 15;
    const int m0 = blockIdx.x * 64;

    f32x4 acc[4][8];
#pragma unroll
    for (int i = 0; i < 4; ++i)
#pragma unroll
        for (int j = 0; j < 8; ++j) acc[i][j] = (f32x4){0.f, 0.f, 0.f, 0.f};

    const float* Ab = A + (size_t)(m0 + l15) * KIN + quad * 8;
    const short* Bb = Wt + (size_t)(wv * 128 + l15) * KIN + quad * 8;

    for (int k0 = 0; k0 < KIN; k0 += 32) {
        bf16x8 af[4], bfr[8];
#pragma unroll
        for (int mi = 0; mi < 4; ++mi) {
            const float* p = Ab + (size_t)mi * 16 * KIN + k0;
            float4 u = *reinterpret_cast<const float4*>(p);
            float4 v = *reinterpret_cast<const float4*>(p + 4);
            af[mi] = cvt8(u, v);
        }
#pragma unroll
        for (int ni = 0; ni < 8; ++ni)
            bfr[ni] = *reinterpret_cast<const bf16x8*>(Bb + (size_t)ni * 16 * KIN + k0);
#pragma unroll
        for (int mi = 0; mi < 4; ++mi)
#pragma unroll
            for (int ni = 0; ni < 8; ++ni)
                acc[mi][ni] = __builtin_amdgcn_mfma_f32_16x16x32_bf16(af[mi], bfr[ni], acc[mi][ni], 0, 0, 0);
    }
    // epilogue: +bias; proj[row][col] scalar + projT[col][row] 8B packed
#pragma unroll
    for (int ni = 0; ni < 8; ++ni) {
        int col = wv * 128 + ni * 16 + l15;
        float bv = bias[col];
#pragma unroll
        for (int mi = 0; mi < 4; ++mi) {
            int row0 = m0 + mi * 16 + quad * 4;
            s4v t;
#pragma unroll
            for (int r = 0; r < 4; ++r) {
                short v = f2bf(acc[mi][ni][r] + bv);
                t[r] = v;
                proj[(size_t)(row0 + r) * DOUT + col] = v;
            }
            *reinterpret_cast<s4v*>(projT + (size_t)col * (Bn * Nn) + row0) = t;
        }
    }
}

// ---------------- sims[b][c][n] = ccp . proj  (K=512), barrier-free ----------------
// block 64c x 128n, 4 waves, wave 32c x 64n. ccp_bf (64 KB) L2/L1-resident;
// proj streamed. Direct fragments, no LDS, no syncthreads.
__global__ __launch_bounds__(256) void k_sims(
    const short* __restrict__ ccp_bf, const short* __restrict__ proj,
    float* __restrict__ sims) {
    const int tid = threadIdx.x, lane = tid & 63, wv = tid >> 6;
    const int quad = lane >> 4, l15 = lane & 15;
    const int b = blockIdx.x >> 6, nt = blockIdx.x & 63;
    const int n0 = nt * 128;
    const int wm = wv & 1, wn = wv >> 1;

    f32x4 acc[2][4];
#pragma unroll
    for (int i = 0; i < 2; ++i)
#pragma unroll
        for (int j = 0; j < 4; ++j) acc[i][j] = (f32x4){0.f, 0.f, 0.f, 0.f};

    const short* Ab = ccp_bf + (size_t)(wm * 32 + l15) * DOUT + quad * 8;
    const short* Bb = proj + (size_t)(b * Nn + n0 + wn * 64 + l15) * DOUT + quad * 8;

    for (int k0 = 0; k0 < DOUT; k0 += 32) {
        bf16x8 af[2], bfr[4];
#pragma unroll
        for (int mi = 0; mi < 2; ++mi)
            af[mi] = *reinterpret_cast<const bf16x8*>(Ab + (size_t)mi * 16 * DOUT + k0);
#pragma unroll
        for (int ni = 0; ni < 4; ++ni)
            bfr[ni] = *reinterpret_cast<const bf16x8*>(Bb + (size_t)ni * 16 * DOUT + k0);
#pragma unroll
        for (int mi = 0; mi < 2; ++mi)
#pragma unroll
            for (int ni = 0; ni < 4; ++ni)
                acc[mi][ni] = __builtin_amdgcn_mfma_f32_16x16x32_bf16(af[mi], bfr[ni], acc[mi][ni], 0, 0, 0);
    }
#pragma unroll
    for (int mi = 0; mi < 2; ++mi)
#pragma unroll
        for (int ni = 0; ni < 4; ++ni)
#pragma unroll
            for (int r = 0; r < 4; ++r) {
                int c = wm * 32 + mi * 16 + quad * 4 + r;
                int n = n0 + wn * 64 + ni * 16 + l15;
                sims[((size_t)b * NC + c) * Nn + n] = acc[mi][ni][r];
            }
}

// ---------------- softmax over n (in-place on d_out) + bf16 copy, float4 ----------------
__global__ __launch_bounds__(256) void k_softmax(
    float* __restrict__ aw, const unsigned char* __restrict__ mask,
    short* __restrict__ aw_bf) {
    __shared__ float red[8];
    const int tid = threadIdx.x, lane = tid & 63, wv = tid >> 6;
    const int b = blockIdx.x >> 6, c = blockIdx.x & 63;
    float4* p4 = reinterpret_cast<float4*>(aw + ((size_t)b * NC + c) * Nn);
    s4v* q4 = reinterpret_cast<s4v*>(aw_bf + ((size_t)b * NC + c) * Nn);
    const uchar4* mp4 = reinterpret_cast<const uchar4*>(mask + (size_t)b * Nn);

    float4 v[8];
    float mx = -INFINITY;
#pragma unroll
    for (int i = 0; i < 8; ++i) {
        int idx = tid + i * 256;
        float4 x = p4[idx];
        uchar4 m = mp4[idx];
        if (m.x) x.x = -INFINITY;
        if (m.y) x.y = -INFINITY;
        if (m.z) x.z = -INFINITY;
        if (m.w) x.w = -INFINITY;
        v[i] = x;
        mx = fmaxf(mx, fmaxf(fmaxf(x.x, x.y), fmaxf(x.z, x.w)));
    }
    for (int off = 32; off; off >>= 1) mx = fmaxf(mx, __shfl_xor(mx, off));
    if (lane == 0) red[wv] = mx;
    __syncthreads();
    mx = fmaxf(fmaxf(red[0], red[1]), fmaxf(red[2], red[3]));
    __syncthreads();

    float s = 0.f;
#pragma unroll
    for (int i = 0; i < 8; ++i) {
        v[i].x = expf(v[i].x - mx); s += v[i].x;
        v[i].y = expf(v[i].y - mx); s += v[i].y;
        v[i].z = expf(v[i].z - mx); s += v[i].z;
        v[i].w = expf(v[i].w - mx); s += v[i].w;
    }
    for (int off = 32; off; off >>= 1) s += __shfl_xor(s, off);
    if (lane == 0) red[wv] = s;
    __syncthreads();
    s = red[0] + red[1] + red[2] + red[3];
    float inv = 1.f / s;
#pragma unroll
    for (int i = 0; i < 8; ++i) {
        int idx = tid + i * 256;
        float4 x = v[i];
        x.x *= inv; x.y *= inv; x.z *= inv; x.w *= inv;
        p4[idx] = x;
        s4v t;
        t[0] = f2bf(x.x); t[1] = f2bf(x.y); t[2] = f2bf(x.z); t[3] = f2bf(x.w);
        q4[idx] = t;
    }
}

// ---------------- aggregation: partial[b][ks][c][d], split-K=16, barrier-free ----------------
// A = aw_bf [c][n] n-contig, B = projT [d][n] n-contig. block 64c x 128d,
// 4 waves, wave 32c x 64d, BK=32, 16 iters over 512-n chunk. No LDS.
__global__ __launch_bounds__(256) void k_agg(
    const short* __restrict__ aw_bf, const short* __restrict__ projT,
    float* __restrict__ partial) {
    const int tid = threadIdx.x, lane = tid & 63, wv = tid >> 6;
    const int quad = lane >> 4, l15 = lane & 15;
    const int b = blockIdx.x >> 6, dt = (blockIdx.x >> 4) & 3, ks = blockIdx.x & 15;
    const int d0 = dt * 128;
    const int wm = wv & 1, wn = wv >> 1;

    f32x4 acc[2][4];
#pragma unroll
    for (int i = 0; i < 2; ++i)
#pragma unroll
        for (int j = 0; j < 4; ++j) acc[i][j] = (f32x4){0.f, 0.f, 0.f, 0.f};

    const int nb0 = ks * 512;
    const short* Ab = aw_bf + ((size_t)b * NC + wm * 32 + l15) * Nn + nb0 + quad * 8;
    const short* Bb = projT + (size_t)(d0 + wn * 64 + l15) * (Bn * Nn) + b * Nn + nb0 + quad * 8;

    for (int nb = 0; nb < 512; nb += 32) {
        bf16x8 af[2], bfr[4];
#pragma unroll
        for (int mi = 0; mi < 2; ++mi)
            af[mi] = *reinterpret_cast<const bf16x8*>(Ab + (size_t)mi * 16 * Nn + nb);
#pragma unroll
        for (int ni = 0; ni < 4; ++ni)
            bfr[ni] = *reinterpret_cast<const bf16x8*>(Bb + (size_t)ni * 16 * (Bn * Nn) + nb);
#pragma unroll
        for (int mi = 0; mi < 2; ++mi)
#pragma unroll
            for (int ni = 0; ni < 4; ++ni)
                acc[mi][ni] = __builtin_amdgcn_mfma_f32_16x16x32_bf16(af[mi], bfr[ni], acc[mi][ni], 0, 0, 0);
    }
#pragma unroll
    for (int mi = 0; mi < 2; ++mi)
#pragma unroll
        for (int ni = 0; ni < 4; ++ni)
#pragma unroll
            for (int r = 0; r < 4; ++r) {
                int c = wm * 32 + mi * 16 + quad * 4 + r;
                int d = d0 + wn * 64 + ni * 16 + l15;
                partial[(((size_t)b * 16 + ks) * NC + c) * DOUT + d] = acc[mi][ni][r];
            }
}

// ---------------- LN: sum 16 partials + ccp residual, normalize, store ----------------
__global__ __launch_bounds__(256) void k_ln(
    const float* __restrict__ partial, const float* __restrict__ ccp,
    const float* __restrict__ gamma, const float* __restrict__ beta,
    float* __restrict__ out) {
    __shared__ float red[16];
    const int tid = threadIdx.x, lane = tid & 63, wv = tid >> 6;
    const int b = blockIdx.x >> 6, c = blockIdx.x & 63;
    float v0 = ccp[c * DOUT + tid], v1 = ccp[c * DOUT + tid + 256];
#pragma unroll
    for (int ks = 0; ks < 16; ++ks) {
        const float* pp = partial + (((size_t)b * 16 + ks) * NC + c) * DOUT;
        v0 += pp[tid];
        v1 += pp[tid + 256];
    }
    float s = v0 + v1, sq = v0 * v0 + v1 * v1;
    for (int off = 32; off; off >>= 1) {
        s += __shfl_xor(s, off);
        sq += __shfl_xor(sq, off);
    }
    if (lane == 0) { red[wv] = s; red[8 + wv] = sq; }
    __syncthreads();
    s = red[0] + red[1] + red[2] + red[3];
    sq = red[8] + red[9] + red[10] + red[11];
    float mu = s * (1.f / 512.f);
    float var = sq * (1.f / 512.f) - mu * mu;
    float rs = rsqrtf(var + LN_EPS);
    size_t base = ((size_t)b * NC + c) * DOUT;
    out[base + tid] = (v0 - mu) * rs * gamma[tid] + beta[tid];
    out[base + tid + 256] = (v1 - mu) * rs * gamma[tid + 256] + beta[tid + 256];
}

extern "C" void kernel_launch(void* const* d_in, const int* in_sizes, int n_in,
                              void* d_out, int out_size, void* d_ws, size_t ws_size,
                              hipStream_t stream) {
    const float* node_emb = (const float*)d_in[0];
    const unsigned char* mask = (const unsigned char*)d_in[1];
    const float* cc = (const float*)d_in[2];
    const float* Wn = (const float*)d_in[3];
    const float* bn = (const float*)d_in[4];
    const float* Wc = (const float*)d_in[5];
    const float* bc = (const float*)d_in[6];
    const float* gamma = (const float*)d_in[7];
    const float* beta = (const float*)d_in[8];
    float* out = (float*)d_out;

    char* ws = (char*)d_ws;
    short* proj   = (short*)(ws);                   //  67,108,864 B  [65536][512] bf16
    short* projT  = (short*)(ws + 67108864);        //  67,108,864 B  [512][65536] bf16
    short* aw_bf  = (short*)(ws + 134217728);       //   8,388,608 B  [8][64][8192] bf16
    float* ccp_f  = (float*)(ws + 142606336);       //     131,072 B
    short* ccp_bf = (short*)(ws + 142737408);       //      65,536 B
    short* Wt     = (short*)(ws + 142802944);       //   1,048,576 B  [512][1024] bf16
    float* partial= (float*)(ws + 143851520);       //  33,554,432 B  [8][16][64][512] f32

    float* sims = out + (size_t)Bn * NC * DOUT;     // aw region of d_out, scratch

    k_prep_w<<<128, 256, 0, stream>>>(Wn, Wt);
    k_prep_c<<<128, 256, 0, stream>>>(cc, Wc, bc, ccp_f, ccp_bf);
    k_gemm1<<<1024, 256, 0, stream>>>(node_emb, Wt, bn, proj, projT);
    k_sims<<<512, 256, 0, stream>>>(ccp_bf, proj, sims);
    k_softmax<<<512, 256, 0, stream>>>(sims, mask, aw_bf);
    k_agg<<<512, 256, 0, stream>>>(aw_bf, projT, partial);
    k_ln<<<512, 256, 0, stream>>>(partial, ccp_f, gamma, beta, out);
}